// Round 8
// baseline (367.827 us; speedup 1.0000x reference)
//
#include <hip/hip_runtime.h>
#include <math.h>

#define N_NODES 50000
#define D_MODEL 128
#define N_HEADS 8
#define HEAD_C 16
#define E_DIM 16
#define N_EDGES 800000

typedef __attribute__((ext_vector_type(8))) short bf16x8;
typedef __attribute__((ext_vector_type(4))) float f32x4;

__device__ inline ushort f2bf(float f) {
    unsigned u = __float_as_uint(f);
    unsigned r = (u + 0x7fffu + ((u >> 16) & 1u)) >> 16;
    return (ushort)r;
}
__device__ inline float bf2f(ushort h) { return __uint_as_float(((unsigned)h) << 16); }
__device__ inline uint pack2(float a, float b) {
    return (uint)f2bf(a) | ((uint)f2bf(b) << 16);
}

// ---------------- Weight prep: transpose + bf16 cast + kv interleave ----------------
// qkvs row layout (512 cols): [0,128)=q ch m; [128,384)=interleaved kv:
//   m=128+4l+{0,1} -> k channels {2l,2l+1}; m=128+4l+{2,3} -> v channels {2l,2l+1};
// [384,512)=xr ch (m-384). Lane l in node_attn reads q/xr as uint at 2l, kv as uint2 at 128+4l.
__global__ void prep_weights(const float* __restrict__ wq, const float* __restrict__ wk,
                             const float* __restrict__ wv, const float* __restrict__ wsk,
                             const float* __restrict__ bq, const float* __restrict__ bk,
                             const float* __restrict__ bv, const float* __restrict__ bsk,
                             const float* __restrict__ w1, const float* __restrict__ w2,
                             ushort* __restrict__ wqkvsT, float* __restrict__ bqkvs,
                             ushort* __restrict__ w1T, ushort* __restrict__ w2T)
{
    int idx = blockIdx.x * 256 + threadIdx.x;          // 0..65535
    {   // wqkvsT [512][128], rows permuted per layout above
        int m = idx >> 7, kk = idx & 127;
        const float* src; int ch;
        if (m < 128)      { src = wq;  ch = m; }
        else if (m < 384) { int t = m - 128, l = t >> 2, r = t & 3;
                            src = (r < 2) ? wk : wv; ch = 2 * l + (r & 1); }
        else              { src = wsk; ch = m - 384; }
        wqkvsT[idx] = f2bf(src[kk * 128 + ch]);
    }
    if (idx < 256 * 128) {   // w1T [256][128] <- w1[128][256]
        int m = idx >> 7, k = idx & 127;
        w1T[idx] = f2bf(w1[k * 256 + m]);
    }
    if (idx < 128 * 256) {   // w2T [128][256] <- w2[256][128]
        int m = idx >> 8, k = idx & 255;
        w2T[idx] = f2bf(w2[k * 128 + m]);
    }
    if (idx < 512) {
        int m = idx;
        const float* bb; int ch;
        if (m < 128)      { bb = bq;  ch = m; }
        else if (m < 384) { int t = m - 128, l = t >> 2, r = t & 3;
                            bb = (r < 2) ? bk : bv; ch = 2 * l + (r & 1); }
        else              { bb = bsk; ch = m - 384; }
        bqkvs[m] = bb[ch];
    }
}

// ---------------- LayerNorm (LN1 only): one wave per row, bf16 out ----------------
__global__ void ln_kernel(const float* __restrict__ in, const float* __restrict__ g,
                          const float* __restrict__ b, ushort* __restrict__ out, int n)
{
    int node = blockIdx.x * 4 + (threadIdx.x >> 6);
    int lane = threadIdx.x & 63;
    if (node >= n) return;
    size_t base = (size_t)node * D_MODEL;
    float v0 = in[base + lane];
    float v1 = in[base + lane + 64];
    float s  = v0 + v1;
    float ss = v0 * v0 + v1 * v1;
    #pragma unroll
    for (int off = 32; off > 0; off >>= 1) {
        s  += __shfl_xor(s,  off, 64);
        ss += __shfl_xor(ss, off, 64);
    }
    float mu  = s * (1.0f / 128.0f);
    float var = ss * (1.0f / 128.0f) - mu * mu;
    float rs  = rsqrtf(var + 1e-5f);
    out[base + lane]      = f2bf((v0 - mu) * rs * g[lane]      + b[lane]);
    out[base + lane + 64] = f2bf((v1 - mu) * rs * g[lane + 64] + b[lane + 64]);
}

// ---------------- bf16 MFMA GEMM, BM=128 x BN=64 (round-5 proven config) ----------
__global__ __launch_bounds__(256) void mfma_gemm(
    const ushort* __restrict__ A, const ushort* __restrict__ WT,
    const float* __restrict__ bias, const float* __restrict__ addsrc,
    void* __restrict__ Y, int nrows, int K, int M, int act, int outf32)
{
    __shared__ __align__(16) ushort Al[128 * 128];   // 32 KB
    __shared__ __align__(16) ushort Wl[64 * 128];    // 16 KB
    int tid = threadIdx.x;
    int wv = tid >> 6, lane = tid & 63;
    int row0 = blockIdx.x * 128;
    int col0 = blockIdx.y * 64;

    f32x4 acc[2][4];
    #pragma unroll
    for (int i = 0; i < 2; ++i)
        #pragma unroll
        for (int j = 0; j < 4; ++j) acc[i][j] = (f32x4){0.f, 0.f, 0.f, 0.f};

    for (int kc = 0; kc < K; kc += 128) {
        __syncthreads();
        #pragma unroll
        for (int i = 0; i < 8; ++i) {
            int c = tid + i * 256;
            int r = c >> 4, c16 = c & 15;
            int gr = row0 + r;
            ulonglong2 val = {0ull, 0ull};
            if (gr < nrows) val = *(const ulonglong2*)(A + (size_t)gr * K + kc + c16 * 8);
            int byte = r * 256 + ((c16 * 16) ^ ((r & 7) << 4));
            *(ulonglong2*)((char*)Al + byte) = val;
        }
        #pragma unroll
        for (int i = 0; i < 4; ++i) {
            int c = tid + i * 256;
            int r = c >> 4, c16 = c & 15;
            ulonglong2 val = *(const ulonglong2*)(WT + (size_t)(col0 + r) * K + kc + c16 * 8);
            int byte = r * 256 + ((c16 * 16) ^ ((r & 7) << 4));
            *(ulonglong2*)((char*)Wl + byte) = val;
        }
        __syncthreads();
        #pragma unroll
        for (int ks = 0; ks < 4; ++ks) {
            bf16x8 af[2], bfr[4];
            #pragma unroll
            for (int rt = 0; rt < 2; ++rt) {
                int r = wv * 32 + rt * 16 + (lane & 15);
                int byte = r * 256 + ((ks * 64 + (lane >> 4) * 16) ^ ((r & 7) << 4));
                af[rt] = *(const bf16x8*)((const char*)Al + byte);
            }
            #pragma unroll
            for (int ct = 0; ct < 4; ++ct) {
                int r = ct * 16 + (lane & 15);
                int byte = r * 256 + ((ks * 64 + (lane >> 4) * 16) ^ ((r & 7) << 4));
                bfr[ct] = *(const bf16x8*)((const char*)Wl + byte);
            }
            #pragma unroll
            for (int rt = 0; rt < 2; ++rt)
                #pragma unroll
                for (int ct = 0; ct < 4; ++ct)
                    acc[rt][ct] = __builtin_amdgcn_mfma_f32_16x16x32_bf16(
                        af[rt], bfr[ct], acc[rt][ct], 0, 0, 0);
        }
    }
    #pragma unroll
    for (int rt = 0; rt < 2; ++rt) {
        #pragma unroll
        for (int ct = 0; ct < 4; ++ct) {
            int gcol = col0 + ct * 16 + (lane & 15);
            float bv = bias[gcol];
            #pragma unroll
            for (int r = 0; r < 4; ++r) {
                int grow = row0 + wv * 32 + rt * 16 + (lane >> 4) * 4 + r;
                if (grow >= nrows) continue;
                float val = acc[rt][ct][r] + bv;
                if (act == 1)
                    val = 0.5f * val * (1.0f + erff(val * 0.70710678118654752f));
                size_t idx = (size_t)grow * M + gcol;
                if (outf32) {
                    float* Yf = (float*)Y;
                    if (addsrc) val += addsrc[idx];
                    Yf[idx] = val;
                } else {
                    ((ushort*)Y)[idx] = f2bf(val);
                }
            }
        }
    }
}

// ---------------- Counting sort of edges by destination ----------------
__global__ void hist_kernel(const int* __restrict__ dst, int* __restrict__ deg)
{
    int e = blockIdx.x * 256 + threadIdx.x;
    if (e < N_EDGES) atomicAdd(&deg[dst[e]], 1);
}

__global__ void scan1_kernel(const int* __restrict__ deg, int* __restrict__ off,
                             int* __restrict__ bsum)
{
    __shared__ int sm[256];
    int i = blockIdx.x * 256 + threadIdx.x;
    int v = (i < N_NODES) ? deg[i] : 0;
    sm[threadIdx.x] = v;
    __syncthreads();
    #pragma unroll
    for (int d = 1; d < 256; d <<= 1) {
        int t = (threadIdx.x >= d) ? sm[threadIdx.x - d] : 0;
        __syncthreads();
        sm[threadIdx.x] += t;
        __syncthreads();
    }
    if (i < N_NODES) off[i] = sm[threadIdx.x] - v;
    if (threadIdx.x == 255) bsum[blockIdx.x] = sm[255];
}

__global__ void scan2_kernel(int* __restrict__ bsum, int nb)
{
    __shared__ int sm[256];
    int v = (threadIdx.x < nb) ? bsum[threadIdx.x] : 0;
    sm[threadIdx.x] = v;
    __syncthreads();
    #pragma unroll
    for (int d = 1; d < 256; d <<= 1) {
        int t = (threadIdx.x >= d) ? sm[threadIdx.x - d] : 0;
        __syncthreads();
        sm[threadIdx.x] += t;
        __syncthreads();
    }
    if (threadIdx.x < nb) bsum[threadIdx.x] = sm[threadIdx.x] - v;
}

__global__ void scan3_kernel(int* __restrict__ off, const int* __restrict__ bsum,
                             int* __restrict__ cursor)
{
    int i = blockIdx.x * 256 + threadIdx.x;
    if (i < N_NODES) {
        int o = off[i] + bsum[blockIdx.x];
        off[i] = o;
        cursor[i] = o;
    }
}

// scatter: src id + bf16 edge_attr row in destination-sorted order
// (random writes here buy SEQUENTIAL hot-loop reads in node_attn — r6 lesson)
__global__ void scatter_kernel(const int* __restrict__ dst, const int* __restrict__ src,
                               const float* __restrict__ eattr, int* __restrict__ cursor,
                               int* __restrict__ src_s, ushort* __restrict__ eattr_s)
{
    int e = blockIdx.x * 256 + threadIdx.x;
    if (e < N_EDGES) {
        int p = atomicAdd(&cursor[dst[e]], 1);
        src_s[p] = src[e];
        const float4* s4 = (const float4*)(eattr + (size_t)e * E_DIM);
        float4 f0 = s4[0], f1 = s4[1], f2 = s4[2], f3 = s4[3];
        uint4 u0, u1;
        u0.x = pack2(f0.x, f0.y); u0.y = pack2(f0.z, f0.w);
        u0.z = pack2(f1.x, f1.y); u0.w = pack2(f1.z, f1.w);
        u1.x = pack2(f2.x, f2.y); u1.y = pack2(f2.z, f2.w);
        u1.z = pack2(f3.x, f3.y); u1.w = pack2(f3.z, f3.w);
        uint4* d4 = (uint4*)(eattr_s + (size_t)p * E_DIM);
        d4[0] = u0; d4[1] = u1;
    }
}

// ---------------- Fused node attention + beta gate + residual + LN2 ----------------
// Lane l owns head h = l>>3, channels 2l, 2l+1. kv interleaved: one uint2 gather/edge.
// Depth-1 software pipeline: edge i+1's loads issue before edge i's compute.
// score pre-scaled by 1/4; no running max (exp clamp 60); LN2 fused in epilogue.
#define ATTN_COMPUTE(KV, EAP) do {                                                   \
    float ea0_ = bf2f((ushort)(EAP)), ea1_ = bf2f((ushort)((EAP) >> 16));            \
    float p_ = q0 * bf2f((ushort)(KV).x) + q1 * bf2f((ushort)((KV).x >> 16))         \
             + ea0_ * qp0 + ea1_ * qp1;                                              \
    p_ += __shfl_xor(p_, 1, 64);                                                     \
    p_ += __shfl_xor(p_, 2, 64);                                                     \
    p_ += __shfl_xor(p_, 4, 64);                                                     \
    float w_ = __expf(fminf(p_, 60.f));                                              \
    S  += w_;                                                                        \
    A0 += w_ * bf2f((ushort)(KV).y);                                                 \
    A1 += w_ * bf2f((ushort)((KV).y >> 16));                                         \
    E0 += w_ * ea0_;                                                                 \
    E1 += w_ * ea1_;                                                                 \
} while (0)

__global__ void node_attn(const ushort* __restrict__ qkvs, const float* __restrict__ x,
                          const float* __restrict__ we, const float* __restrict__ wbeta,
                          const float* __restrict__ ln2g, const float* __restrict__ ln2b,
                          const int* __restrict__ off, const int* __restrict__ deg,
                          const int* __restrict__ src_s, const ushort* __restrict__ eattr_s,
                          float* __restrict__ xnew, ushort* __restrict__ h2)
{
    __shared__ float wl[E_DIM * 128];     // we row-major [16][128], 8 KB
    __shared__ float weT[128 * 17];       // we transposed [128][16+pad], 8.5 KB
    __shared__ float sc4[4][128];         // per-wave scratch, 2 KB
    for (int t = threadIdx.x; t < E_DIM * 32; t += 256)
        *(float4*)&wl[t * 4] = *(const float4*)&we[t * 4];
    for (int t = threadIdx.x; t < E_DIM * 128; t += 256) {
        int j = t >> 7, ch = t & 127;
        weT[ch * 17 + j] = we[t];
    }
    __syncthreads();

    int nl   = threadIdx.x >> 6;
    int node = blockIdx.x * 4 + nl;
    int lane = threadIdx.x & 63;
    if (node >= N_NODES) return;

    int j2 = (lane & 7) * 2;              // this lane's ea component pair
    int hb = (lane >> 3) * 16;            // head channel base

    size_t nb = (size_t)node * 512;
    uint qp = *(const uint*)(qkvs + nb + 2 * lane);
    float q0r = bf2f((ushort)qp), q1r = bf2f((ushort)(qp >> 16));

    // qproj[h, j] = sum_c we[j, h*16+c] * q[h*16+c]  (this lane: j = j2, j2+1)
    sc4[nl][2 * lane]     = q0r;
    sc4[nl][2 * lane + 1] = q1r;
    float qp0 = 0.f, qp1 = 0.f;
    #pragma unroll
    for (int c = 0; c < 16; ++c) {
        float qc = sc4[nl][hb + c];
        qp0 += qc * weT[(hb + c) * 17 + j2];
        qp1 += qc * weT[(hb + c) * 17 + j2 + 1];
    }
    float q0 = q0r * 0.25f, q1 = q1r * 0.25f;   // fold 1/sqrt(C)
    qp0 *= 0.25f; qp1 *= 0.25f;

    float S = 0.f, A0 = 0.f, A1 = 0.f, E0 = 0.f, E1 = 0.f;
    int o = off[node], dg = deg[node];

    if (dg > 0) {
        int sv0 = src_s[o];
        uint eap0 = *(const uint*)(eattr_s + (size_t)o * E_DIM + j2);
        uint2 kv0 = *(const uint2*)(qkvs + (size_t)sv0 * 512 + 128 + 4 * lane);
        for (int i = 1; i < dg; ++i) {
            int sv1 = src_s[o + i];
            uint eap1 = *(const uint*)(eattr_s + (size_t)(o + i) * E_DIM + j2);
            uint2 kv1 = *(const uint2*)(qkvs + (size_t)sv1 * 512 + 128 + 4 * lane);
            ATTN_COMPUTE(kv0, eap0);
            kv0 = kv1; eap0 = eap1;
        }
        ATTN_COMPUTE(kv0, eap0);
    }

    // easum post-transform: ep[ch] = sum_j easum[h, j] * we[j, ch], ch = 2l, 2l+1
    sc4[nl][2 * lane]     = E0;
    sc4[nl][2 * lane + 1] = E1;
    float ep0 = 0.f, ep1 = 0.f;
    #pragma unroll
    for (int j = 0; j < 16; ++j) {
        float es = sc4[nl][hb + j];
        ep0 += es * wl[j * 128 + 2 * lane];
        ep1 += es * wl[j * 128 + 2 * lane + 1];
    }

    float rinv = 1.f / (S + 1e-16f);
    float o0 = (A0 + ep0) * rinv;
    float o1 = (A1 + ep1) * rinv;

    uint xrp = *(const uint*)(qkvs + nb + 384 + 2 * lane);
    float xr0 = bf2f((ushort)xrp), xr1 = bf2f((ushort)(xrp >> 16));
    float2 wb0 = *(const float2*)&wbeta[2 * lane];
    float2 wb1 = *(const float2*)&wbeta[128 + 2 * lane];
    float2 wb2 = *(const float2*)&wbeta[256 + 2 * lane];
    float dot = o0 * wb0.x + o1 * wb0.y + xr0 * wb1.x + xr1 * wb1.y
              + (o0 - xr0) * wb2.x + (o1 - xr1) * wb2.y;
    #pragma unroll
    for (int w = 32; w > 0; w >>= 1) dot += __shfl_xor(dot, w, 64);
    float beta = 1.f / (1.f + __expf(-dot));

    size_t xb = (size_t)node * D_MODEL + 2 * lane;
    float2 xv = *(const float2*)&x[xb];
    float ox = xv.x + beta * xr0 + (1.f - beta) * o0;
    float oy = xv.y + beta * xr1 + (1.f - beta) * o1;
    *(float2*)&xnew[xb] = make_float2(ox, oy);

    // ---- fused LN2 (values live in wave registers) ----
    float s2  = ox + oy;
    float ss2 = ox * ox + oy * oy;
    #pragma unroll
    for (int w = 32; w > 0; w >>= 1) {
        s2  += __shfl_xor(s2,  w, 64);
        ss2 += __shfl_xor(ss2, w, 64);
    }
    float mu  = s2 * (1.0f / 128.0f);
    float var = ss2 * (1.0f / 128.0f) - mu * mu;
    float rs  = rsqrtf(var + 1e-5f);
    float2 g2 = *(const float2*)&ln2g[2 * lane];
    float2 b2 = *(const float2*)&ln2b[2 * lane];
    float h0 = (ox - mu) * rs * g2.x + b2.x;
    float h1 = (oy - mu) * rs * g2.y + b2.y;
    ((uint*)h2)[(size_t)node * 64 + lane] = pack2(h0, h1);
}

extern "C" void kernel_launch(void* const* d_in, const int* in_sizes, int n_in,
                              void* d_out, int out_size, void* d_ws, size_t ws_size,
                              hipStream_t stream)
{
    const float* x     = (const float*)d_in[0];
    const int*   eidx  = (const int*)  d_in[1];
    const float* eattr = (const float*)d_in[2];
    const float* wq  = (const float*)d_in[3];  const float* bq  = (const float*)d_in[4];
    const float* wk  = (const float*)d_in[5];  const float* bk  = (const float*)d_in[6];
    const float* wv  = (const float*)d_in[7];  const float* bv  = (const float*)d_in[8];
    const float* we  = (const float*)d_in[9];
    const float* wsk = (const float*)d_in[10]; const float* bsk = (const float*)d_in[11];
    const float* wbeta = (const float*)d_in[12];
    const float* ln1g = (const float*)d_in[13]; const float* ln1b = (const float*)d_in[14];
    const float* ln2g = (const float*)d_in[15]; const float* ln2b = (const float*)d_in[16];
    const float* w1 = (const float*)d_in[17]; const float* b1 = (const float*)d_in[18];
    const float* w2 = (const float*)d_in[19]; const float* b2 = (const float*)d_in[20];
    const int* srcp = eidx;
    const int* dstp = eidx + N_EDGES;
    float* out = (float*)d_out;

    char* w = (char*)d_ws;
    size_t o = 0;
    ushort* qkvs_b  = (ushort*)(w + o);                 // [N][512] bf16 q|kv-interleaved|xr
    ushort* hidden_b = qkvs_b;                          // alias: [N][256] bf16 (after attn)
    o += (size_t)N_NODES * 512 * 2;
    float* xnew = (float*)(w + o);  o += (size_t)N_NODES * 128 * 4;
    ushort* eattr_s = (ushort*)(w + o); o += (size_t)N_EDGES * E_DIM * 2;  // bf16, 25.6MB
    int* src_s = (int*)(w + o);     o += (size_t)N_EDGES * 4;
    ushort* xn_b = (ushort*)(w + o);
    ushort* h2_b = xn_b;                                 // alias (LN1 input dead after proj)
    o += (size_t)N_NODES * 128 * 2;
    ushort* wqkvsT = (ushort*)(w + o); o += 512 * 128 * 2;
    ushort* w1T    = (ushort*)(w + o); o += 256 * 128 * 2;
    ushort* w2T    = (ushort*)(w + o); o += 128 * 256 * 2;
    float*  bqkvs  = (float*)(w + o);  o += 4096;
    int* deg    = (int*)(w + o); o += 200704;
    int* offb   = (int*)(w + o); o += 200704;
    int* cursor = (int*)(w + o); o += 200704;
    int* bsum   = (int*)(w + o); o += 4096;

    dim3 blk(256);
    dim3 lngrid((N_NODES + 3) / 4);
    const int NB = (N_NODES + 255) / 256;
    const int EB = (N_EDGES + 255) / 256;
    const int GB = (N_NODES + 127) / 128;

    prep_weights<<<dim3(256), blk, 0, stream>>>(wq, wk, wv, wsk, bq, bk, bv, bsk,
                                                w1, w2, wqkvsT, bqkvs, w1T, w2T);
    ln_kernel<<<lngrid, blk, 0, stream>>>(x, ln1g, ln1b, xn_b, N_NODES);
    mfma_gemm<<<dim3(GB, 8), blk, 0, stream>>>(xn_b, wqkvsT, bqkvs, nullptr,
                                               qkvs_b, N_NODES, 128, 512, 0, 0);
    hipMemsetAsync(deg, 0, (size_t)N_NODES * 4, stream);
    hist_kernel<<<dim3(EB), blk, 0, stream>>>(dstp, deg);
    scan1_kernel<<<dim3(NB), blk, 0, stream>>>(deg, offb, bsum);
    scan2_kernel<<<dim3(1), blk, 0, stream>>>(bsum, NB);
    scan3_kernel<<<dim3(NB), blk, 0, stream>>>(offb, bsum, cursor);
    scatter_kernel<<<dim3(EB), blk, 0, stream>>>(dstp, srcp, eattr, cursor, src_s, eattr_s);
    node_attn<<<lngrid, blk, 0, stream>>>(qkvs_b, x, we, wbeta, ln2g, ln2b,
                                          offb, deg, src_s, eattr_s, xnew, h2_b);
    mfma_gemm<<<dim3(GB, 4), blk, 0, stream>>>(h2_b, w1T, b1, nullptr,
                                               hidden_b, N_NODES, 128, 256, 1, 0);
    mfma_gemm<<<dim3(GB, 2), blk, 0, stream>>>(hidden_b, w2T, b2, xnew,
                                               out, N_NODES, 256, 128, 0, 1);
}

// Round 9
// 330.210 us; speedup vs baseline: 1.1139x; 1.1139x over previous
//
#include <hip/hip_runtime.h>
#include <math.h>

#define N_NODES 50000
#define D_MODEL 128
#define N_HEADS 8
#define HEAD_C 16
#define E_DIM 16
#define N_EDGES 800000

typedef __attribute__((ext_vector_type(8))) short bf16x8;
typedef __attribute__((ext_vector_type(4))) float f32x4;

__device__ inline ushort f2bf(float f) {
    unsigned u = __float_as_uint(f);
    unsigned r = (u + 0x7fffu + ((u >> 16) & 1u)) >> 16;
    return (ushort)r;
}
__device__ inline float bf2f(ushort h) { return __uint_as_float(((unsigned)h) << 16); }
__device__ inline uint pack2(float a, float b) {
    return (uint)f2bf(a) | ((uint)f2bf(b) << 16);
}

// ---------------- Weight prep: transpose + bf16 cast (natural column order) ----
__global__ void prep_weights(const float* __restrict__ wq, const float* __restrict__ wk,
                             const float* __restrict__ wv, const float* __restrict__ wsk,
                             const float* __restrict__ bq, const float* __restrict__ bk,
                             const float* __restrict__ bv, const float* __restrict__ bsk,
                             const float* __restrict__ w1, const float* __restrict__ w2,
                             ushort* __restrict__ wqkvsT, float* __restrict__ bqkvs,
                             ushort* __restrict__ w1T, ushort* __restrict__ w2T)
{
    int idx = blockIdx.x * 256 + threadIdx.x;          // 0..65535
    {   // wqkvsT [512][128] <- {wq|wk|wv|wsk}[128][128] transposed
        int m = idx >> 7, kk = idx & 127;
        int b = m >> 7, ch = m & 127;
        const float* src = (b == 0) ? wq : (b == 1) ? wk : (b == 2) ? wv : wsk;
        wqkvsT[idx] = f2bf(src[kk * 128 + ch]);
    }
    if (idx < 256 * 128) {   // w1T [256][128] <- w1[128][256]
        int m = idx >> 7, k = idx & 127;
        w1T[idx] = f2bf(w1[k * 256 + m]);
    }
    if (idx < 128 * 256) {   // w2T [128][256] <- w2[256][128]
        int m = idx >> 8, k = idx & 255;
        w2T[idx] = f2bf(w2[k * 128 + m]);
    }
    if (idx < 512) {
        int b = idx >> 7, ch = idx & 127;
        const float* bb = (b == 0) ? bq : (b == 1) ? bk : (b == 2) ? bv : bsk;
        bqkvs[idx] = bb[ch];
    }
}

// ---------------- LayerNorm (LN1): one wave per row, bf16 out ----------------
__global__ void ln_kernel(const float* __restrict__ in, const float* __restrict__ g,
                          const float* __restrict__ b, ushort* __restrict__ out, int n)
{
    int node = blockIdx.x * 4 + (threadIdx.x >> 6);
    int lane = threadIdx.x & 63;
    if (node >= n) return;
    size_t base = (size_t)node * D_MODEL;
    float v0 = in[base + lane];
    float v1 = in[base + lane + 64];
    float s  = v0 + v1;
    float ss = v0 * v0 + v1 * v1;
    #pragma unroll
    for (int off = 32; off > 0; off >>= 1) {
        s  += __shfl_xor(s,  off, 64);
        ss += __shfl_xor(ss, off, 64);
    }
    float mu  = s * (1.0f / 128.0f);
    float var = ss * (1.0f / 128.0f) - mu * mu;
    float rs  = rsqrtf(var + 1e-5f);
    out[base + lane]      = f2bf((v0 - mu) * rs * g[lane]      + b[lane]);
    out[base + lane + 64] = f2bf((v1 - mu) * rs * g[lane + 64] + b[lane + 64]);
}

// ---------------- bf16 MFMA GEMM, BM=128 x BN=64 (round-5 proven config) ----------
__global__ __launch_bounds__(256) void mfma_gemm(
    const ushort* __restrict__ A, const ushort* __restrict__ WT,
    const float* __restrict__ bias, const float* __restrict__ addsrc,
    void* __restrict__ Y, int nrows, int K, int M, int act, int outf32)
{
    __shared__ __align__(16) ushort Al[128 * 128];   // 32 KB
    __shared__ __align__(16) ushort Wl[64 * 128];    // 16 KB
    int tid = threadIdx.x;
    int wv = tid >> 6, lane = tid & 63;
    int row0 = blockIdx.x * 128;
    int col0 = blockIdx.y * 64;

    f32x4 acc[2][4];
    #pragma unroll
    for (int i = 0; i < 2; ++i)
        #pragma unroll
        for (int j = 0; j < 4; ++j) acc[i][j] = (f32x4){0.f, 0.f, 0.f, 0.f};

    for (int kc = 0; kc < K; kc += 128) {
        __syncthreads();
        #pragma unroll
        for (int i = 0; i < 8; ++i) {
            int c = tid + i * 256;
            int r = c >> 4, c16 = c & 15;
            int gr = row0 + r;
            ulonglong2 val = {0ull, 0ull};
            if (gr < nrows) val = *(const ulonglong2*)(A + (size_t)gr * K + kc + c16 * 8);
            int byte = r * 256 + ((c16 * 16) ^ ((r & 7) << 4));
            *(ulonglong2*)((char*)Al + byte) = val;
        }
        #pragma unroll
        for (int i = 0; i < 4; ++i) {
            int c = tid + i * 256;
            int r = c >> 4, c16 = c & 15;
            ulonglong2 val = *(const ulonglong2*)(WT + (size_t)(col0 + r) * K + kc + c16 * 8);
            int byte = r * 256 + ((c16 * 16) ^ ((r & 7) << 4));
            *(ulonglong2*)((char*)Wl + byte) = val;
        }
        __syncthreads();
        #pragma unroll
        for (int ks = 0; ks < 4; ++ks) {
            bf16x8 af[2], bfr[4];
            #pragma unroll
            for (int rt = 0; rt < 2; ++rt) {
                int r = wv * 32 + rt * 16 + (lane & 15);
                int byte = r * 256 + ((ks * 64 + (lane >> 4) * 16) ^ ((r & 7) << 4));
                af[rt] = *(const bf16x8*)((const char*)Al + byte);
            }
            #pragma unroll
            for (int ct = 0; ct < 4; ++ct) {
                int r = ct * 16 + (lane & 15);
                int byte = r * 256 + ((ks * 64 + (lane >> 4) * 16) ^ ((r & 7) << 4));
                bfr[ct] = *(const bf16x8*)((const char*)Wl + byte);
            }
            #pragma unroll
            for (int rt = 0; rt < 2; ++rt)
                #pragma unroll
                for (int ct = 0; ct < 4; ++ct)
                    acc[rt][ct] = __builtin_amdgcn_mfma_f32_16x16x32_bf16(
                        af[rt], bfr[ct], acc[rt][ct], 0, 0, 0);
        }
    }
    #pragma unroll
    for (int rt = 0; rt < 2; ++rt) {
        #pragma unroll
        for (int ct = 0; ct < 4; ++ct) {
            int gcol = col0 + ct * 16 + (lane & 15);
            float bv = bias[gcol];
            #pragma unroll
            for (int r = 0; r < 4; ++r) {
                int grow = row0 + wv * 32 + rt * 16 + (lane >> 4) * 4 + r;
                if (grow >= nrows) continue;
                float val = acc[rt][ct][r] + bv;
                if (act == 1)
                    val = 0.5f * val * (1.0f + erff(val * 0.70710678118654752f));
                size_t idx = (size_t)grow * M + gcol;
                if (outf32) {
                    float* Yf = (float*)Y;
                    if (addsrc) val += addsrc[idx];
                    Yf[idx] = val;
                } else {
                    ((ushort*)Y)[idx] = f2bf(val);
                }
            }
        }
    }
}

// ---------------- Counting sort of edges by destination ----------------
__global__ void hist_kernel(const int* __restrict__ dst, int* __restrict__ deg)
{
    int e = blockIdx.x * 256 + threadIdx.x;
    if (e < N_EDGES) atomicAdd(&deg[dst[e]], 1);
}

__global__ void scan1_kernel(const int* __restrict__ deg, int* __restrict__ off,
                             int* __restrict__ bsum)
{
    __shared__ int sm[256];
    int i = blockIdx.x * 256 + threadIdx.x;
    int v = (i < N_NODES) ? deg[i] : 0;
    sm[threadIdx.x] = v;
    __syncthreads();
    #pragma unroll
    for (int d = 1; d < 256; d <<= 1) {
        int t = (threadIdx.x >= d) ? sm[threadIdx.x - d] : 0;
        __syncthreads();
        sm[threadIdx.x] += t;
        __syncthreads();
    }
    if (i < N_NODES) off[i] = sm[threadIdx.x] - v;
    if (threadIdx.x == 255) bsum[blockIdx.x] = sm[255];
}

__global__ void scan2_kernel(int* __restrict__ bsum, int nb)
{
    __shared__ int sm[256];
    int v = (threadIdx.x < nb) ? bsum[threadIdx.x] : 0;
    sm[threadIdx.x] = v;
    __syncthreads();
    #pragma unroll
    for (int d = 1; d < 256; d <<= 1) {
        int t = (threadIdx.x >= d) ? sm[threadIdx.x - d] : 0;
        __syncthreads();
        sm[threadIdx.x] += t;
        __syncthreads();
    }
    if (threadIdx.x < nb) bsum[threadIdx.x] = sm[threadIdx.x] - v;
}

__global__ void scan3_kernel(int* __restrict__ off, const int* __restrict__ bsum,
                             int* __restrict__ cursor)
{
    int i = blockIdx.x * 256 + threadIdx.x;
    if (i < N_NODES) {
        int o = off[i] + bsum[blockIdx.x];
        off[i] = o;
        cursor[i] = o;
    }
}

// scatter: src id + bf16 edge_attr row in destination-sorted order
// (random writes here buy SEQUENTIAL hot-loop reads in node_attn — r6 lesson)
__global__ void scatter_kernel(const int* __restrict__ dst, const int* __restrict__ src,
                               const float* __restrict__ eattr, int* __restrict__ cursor,
                               int* __restrict__ src_s, ushort* __restrict__ eattr_s)
{
    int e = blockIdx.x * 256 + threadIdx.x;
    if (e < N_EDGES) {
        int p = atomicAdd(&cursor[dst[e]], 1);
        src_s[p] = src[e];
        const float4* s4 = (const float4*)(eattr + (size_t)e * E_DIM);
        float4 f0 = s4[0], f1 = s4[1], f2 = s4[2], f3 = s4[3];
        uint4 u0, u1;
        u0.x = pack2(f0.x, f0.y); u0.y = pack2(f0.z, f0.w);
        u0.z = pack2(f1.x, f1.y); u0.w = pack2(f1.z, f1.w);
        u1.x = pack2(f2.x, f2.y); u1.y = pack2(f2.z, f2.w);
        u1.z = pack2(f3.x, f3.y); u1.w = pack2(f3.z, f3.w);
        uint4* d4 = (uint4*)(eattr_s + (size_t)p * E_DIM);
        d4[0] = u0; d4[1] = u1;
    }
}

// ---------------- Fused node attention (r7 loop) + beta + residual + LN2 ----------
// Lane l owns head h = l>>3, channels 2l, 2l+1 (j = l&7 -> ea comps 2j, 2j+1).
// qkvs bf16 [N][512] q|k|v|xr; edge payload streams SEQUENTIALLY (src_s, eattr_s).
// 2-way unroll with DUAL accumulator state (compiler-scheduled ILP — r8 lesson:
// do not hand-rotate this loop). score pre-scaled by 1/4; exp clamp 60, no max.
#define ATTN_STEP(P, S, A0, A1, E0, E1) do {                                         \
    int sv_ = src_s[P];                                                              \
    uint eap_ = *(const uint*)(eattr_s + (size_t)(P) * E_DIM + j2);                  \
    float ea0_ = bf2f((ushort)eap_), ea1_ = bf2f((ushort)(eap_ >> 16));              \
    size_t sb_ = (size_t)sv_ * 512;                                                  \
    uint kp_ = *(const uint*)(qkvs + sb_ + 128 + 2 * lane);                          \
    uint vp_ = *(const uint*)(qkvs + sb_ + 256 + 2 * lane);                          \
    float p_ = q0 * bf2f((ushort)kp_) + q1 * bf2f((ushort)(kp_ >> 16))               \
             + ea0_ * qp0 + ea1_ * qp1;                                              \
    p_ += __shfl_xor(p_, 1, 64);                                                     \
    p_ += __shfl_xor(p_, 2, 64);                                                     \
    p_ += __shfl_xor(p_, 4, 64);                                                     \
    float w_ = __expf(fminf(p_, 60.f));                                              \
    S  += w_;                                                                        \
    A0 += w_ * bf2f((ushort)vp_);                                                    \
    A1 += w_ * bf2f((ushort)(vp_ >> 16));                                            \
    E0 += w_ * ea0_;                                                                 \
    E1 += w_ * ea1_;                                                                 \
} while (0)

__global__ void node_attn(const ushort* __restrict__ qkvs, const float* __restrict__ x,
                          const float* __restrict__ we, const float* __restrict__ wbeta,
                          const float* __restrict__ ln2g, const float* __restrict__ ln2b,
                          const int* __restrict__ off, const int* __restrict__ deg,
                          const int* __restrict__ src_s, const ushort* __restrict__ eattr_s,
                          float* __restrict__ xnew, ushort* __restrict__ h2)
{
    __shared__ float wl[E_DIM * 128];     // we row-major [16][128], 8 KB
    __shared__ float weT[128 * 17];       // we transposed [128][16+pad], 8.5 KB
    __shared__ float sc4[4][128];         // per-wave scratch, 2 KB
    for (int t = threadIdx.x; t < E_DIM * 32; t += 256)
        *(float4*)&wl[t * 4] = *(const float4*)&we[t * 4];
    for (int t = threadIdx.x; t < E_DIM * 128; t += 256) {
        int j = t >> 7, ch = t & 127;
        weT[ch * 17 + j] = we[t];
    }
    __syncthreads();

    int nl   = threadIdx.x >> 6;
    int node = blockIdx.x * 4 + nl;
    int lane = threadIdx.x & 63;
    if (node >= N_NODES) return;

    int j2 = (lane & 7) * 2;              // this lane's ea component pair
    int hb = (lane >> 3) * 16;            // head channel base

    size_t nb = (size_t)node * 512;
    uint qp = *(const uint*)(qkvs + nb + 2 * lane);
    float q0r = bf2f((ushort)qp), q1r = bf2f((ushort)(qp >> 16));

    // qproj[h, j] = sum_c we[j, h*16+c] * q[h*16+c]  (this lane: j = j2, j2+1)
    sc4[nl][2 * lane]     = q0r;
    sc4[nl][2 * lane + 1] = q1r;
    float qp0 = 0.f, qp1 = 0.f;
    #pragma unroll
    for (int c = 0; c < 16; ++c) {
        float qc = sc4[nl][hb + c];
        qp0 += qc * weT[(hb + c) * 17 + j2];
        qp1 += qc * weT[(hb + c) * 17 + j2 + 1];
    }
    float q0 = q0r * 0.25f, q1 = q1r * 0.25f;   // fold 1/sqrt(C)
    qp0 *= 0.25f; qp1 *= 0.25f;

    float SA = 0.f, A0a = 0.f, A1a = 0.f, E0a = 0.f, E1a = 0.f;
    float SB = 0.f, A0b = 0.f, A1b = 0.f, E0b = 0.f, E1b = 0.f;

    int o = off[node], dg = deg[node];
    int i = 0;
    for (; i + 2 <= dg; i += 2) {
        ATTN_STEP(o + i,     SA, A0a, A1a, E0a, E1a);
        ATTN_STEP(o + i + 1, SB, A0b, A1b, E0b, E1b);
    }
    if (i < dg)
        ATTN_STEP(o + i, SA, A0a, A1a, E0a, E1a);

    float S  = SA + SB;
    float A0 = A0a + A0b, A1 = A1a + A1b;
    float E0 = E0a + E0b, E1 = E1a + E1b;

    // easum post-transform: ep[ch] = sum_j easum[h, j] * we[j, ch], ch = 2l, 2l+1
    sc4[nl][2 * lane]     = E0;
    sc4[nl][2 * lane + 1] = E1;
    float ep0 = 0.f, ep1 = 0.f;
    #pragma unroll
    for (int j = 0; j < 16; ++j) {
        float es = sc4[nl][hb + j];
        ep0 += es * wl[j * 128 + 2 * lane];
        ep1 += es * wl[j * 128 + 2 * lane + 1];
    }

    float rinv = 1.f / (S + 1e-16f);
    float o0 = (A0 + ep0) * rinv;
    float o1 = (A1 + ep1) * rinv;

    uint xrp = *(const uint*)(qkvs + nb + 384 + 2 * lane);
    float xr0 = bf2f((ushort)xrp), xr1 = bf2f((ushort)(xrp >> 16));
    float2 wb0 = *(const float2*)&wbeta[2 * lane];
    float2 wb1 = *(const float2*)&wbeta[128 + 2 * lane];
    float2 wb2 = *(const float2*)&wbeta[256 + 2 * lane];
    float dot = o0 * wb0.x + o1 * wb0.y + xr0 * wb1.x + xr1 * wb1.y
              + (o0 - xr0) * wb2.x + (o1 - xr1) * wb2.y;
    #pragma unroll
    for (int w = 32; w > 0; w >>= 1) dot += __shfl_xor(dot, w, 64);
    float beta = 1.f / (1.f + __expf(-dot));

    size_t xb = (size_t)node * D_MODEL + 2 * lane;
    float2 xv = *(const float2*)&x[xb];
    float ox = xv.x + beta * xr0 + (1.f - beta) * o0;
    float oy = xv.y + beta * xr1 + (1.f - beta) * o1;
    *(float2*)&xnew[xb] = make_float2(ox, oy);

    // ---- fused LN2 (values live in wave registers) ----
    float s2  = ox + oy;
    float ss2 = ox * ox + oy * oy;
    #pragma unroll
    for (int w = 32; w > 0; w >>= 1) {
        s2  += __shfl_xor(s2,  w, 64);
        ss2 += __shfl_xor(ss2, w, 64);
    }
    float mu  = s2 * (1.0f / 128.0f);
    float var = ss2 * (1.0f / 128.0f) - mu * mu;
    float rs  = rsqrtf(var + 1e-5f);
    float2 g2 = *(const float2*)&ln2g[2 * lane];
    float2 b2 = *(const float2*)&ln2b[2 * lane];
    float h0 = (ox - mu) * rs * g2.x + b2.x;
    float h1 = (oy - mu) * rs * g2.y + b2.y;
    ((uint*)h2)[(size_t)node * 64 + lane] = pack2(h0, h1);
}

extern "C" void kernel_launch(void* const* d_in, const int* in_sizes, int n_in,
                              void* d_out, int out_size, void* d_ws, size_t ws_size,
                              hipStream_t stream)
{
    const float* x     = (const float*)d_in[0];
    const int*   eidx  = (const int*)  d_in[1];
    const float* eattr = (const float*)d_in[2];
    const float* wq  = (const float*)d_in[3];  const float* bq  = (const float*)d_in[4];
    const float* wk  = (const float*)d_in[5];  const float* bk  = (const float*)d_in[6];
    const float* wv  = (const float*)d_in[7];  const float* bv  = (const float*)d_in[8];
    const float* we  = (const float*)d_in[9];
    const float* wsk = (const float*)d_in[10]; const float* bsk = (const float*)d_in[11];
    const float* wbeta = (const float*)d_in[12];
    const float* ln1g = (const float*)d_in[13]; const float* ln1b = (const float*)d_in[14];
    const float* ln2g = (const float*)d_in[15]; const float* ln2b = (const float*)d_in[16];
    const float* w1 = (const float*)d_in[17]; const float* b1 = (const float*)d_in[18];
    const float* w2 = (const float*)d_in[19]; const float* b2 = (const float*)d_in[20];
    const int* srcp = eidx;
    const int* dstp = eidx + N_EDGES;
    float* out = (float*)d_out;

    char* w = (char*)d_ws;
    size_t o = 0;
    ushort* qkvs_b  = (ushort*)(w + o);                 // [N][512] bf16 q|k|v|xr
    ushort* hidden_b = qkvs_b;                          // alias: [N][256] bf16 (after attn)
    o += (size_t)N_NODES * 512 * 2;
    float* xnew = (float*)(w + o);  o += (size_t)N_NODES * 128 * 4;
    ushort* eattr_s = (ushort*)(w + o); o += (size_t)N_EDGES * E_DIM * 2;  // bf16, 25.6MB
    int* src_s = (int*)(w + o);     o += (size_t)N_EDGES * 4;
    ushort* xn_b = (ushort*)(w + o);
    ushort* h2_b = xn_b;                                 // alias (LN1 out dead after proj)
    o += (size_t)N_NODES * 128 * 2;
    ushort* wqkvsT = (ushort*)(w + o); o += 512 * 128 * 2;
    ushort* w1T    = (ushort*)(w + o); o += 256 * 128 * 2;
    ushort* w2T    = (ushort*)(w + o); o += 128 * 256 * 2;
    float*  bqkvs  = (float*)(w + o);  o += 4096;
    int* deg    = (int*)(w + o); o += 200704;
    int* offb   = (int*)(w + o); o += 200704;
    int* cursor = (int*)(w + o); o += 200704;
    int* bsum   = (int*)(w + o); o += 4096;

    dim3 blk(256);
    dim3 lngrid((N_NODES + 3) / 4);
    const int NB = (N_NODES + 255) / 256;
    const int EB = (N_EDGES + 255) / 256;
    const int GB = (N_NODES + 127) / 128;

    prep_weights<<<dim3(256), blk, 0, stream>>>(wq, wk, wv, wsk, bq, bk, bv, bsk,
                                                w1, w2, wqkvsT, bqkvs, w1T, w2T);
    ln_kernel<<<lngrid, blk, 0, stream>>>(x, ln1g, ln1b, xn_b, N_NODES);
    mfma_gemm<<<dim3(GB, 8), blk, 0, stream>>>(xn_b, wqkvsT, bqkvs, nullptr,
                                               qkvs_b, N_NODES, 128, 512, 0, 0);
    hipMemsetAsync(deg, 0, (size_t)N_NODES * 4, stream);
    hist_kernel<<<dim3(EB), blk, 0, stream>>>(dstp, deg);
    scan1_kernel<<<dim3(NB), blk, 0, stream>>>(deg, offb, bsum);
    scan2_kernel<<<dim3(1), blk, 0, stream>>>(bsum, NB);
    scan3_kernel<<<dim3(NB), blk, 0, stream>>>(offb, bsum, cursor);
    scatter_kernel<<<dim3(EB), blk, 0, stream>>>(dstp, srcp, eattr, cursor, src_s, eattr_s);
    node_attn<<<lngrid, blk, 0, stream>>>(qkvs_b, x, we, wbeta, ln2g, ln2b,
                                          offb, deg, src_s, eattr_s, xnew, h2_b);
    mfma_gemm<<<dim3(GB, 4), blk, 0, stream>>>(h2_b, w1T, b1, nullptr,
                                               hidden_b, N_NODES, 128, 256, 1, 0);
    mfma_gemm<<<dim3(GB, 2), blk, 0, stream>>>(hidden_b, w2T, b2, xnew,
                                               out, N_NODES, 256, 128, 0, 1);
}